// Round 5
// baseline (541.549 us; speedup 1.0000x reference)
//
#include <hip/hip_runtime.h>

// NCC loss, fused single pass. Layout [n][1][d][h][w], n=2, d=160, h=192, w=192, f32.
// R10: BARRIER-FREE wave-private structure. Evidence: R6 (cut 33% of LDS reads) and
//   R9 (distance-2 counted-vmcnt pipeline, correct) both changed NOTHING (84-86us,
//   VALU ~48%, LDS pipe ~50%, occupancy 19-26% vs static cap 50%). The remaining
//   suspect is the 4-wave barrier-coupled step: every step costs max-over-waves
//   (sync skew) and ~1.5 resident blocks/CU leave nothing to fill the bubbles.
//   Change: each wave is fully independent.
//     - wave w owns output rows hbase+4w..4w+3; stages its own 8 input rows
//       (4+4 H-halo) of BOTH arrays into a private LDS region (2 buffers).
//       Per-lane array select: seg = r*64+lane in [0,288): arr=seg>=144,
//       row=rem/18, c16=rem%18. global addr is PER-LANE (legal; only the LDS
//       dest is lane-linear, m104/m108): goffL[r] = (arr?J-I:0) + hc*SH + gc.
//     - distance-1 private prefetch: top of step t issues 5 DMAs for slice s+1
//       into buf^1; bottom of step waits s_waitcnt vmcnt(0) lgkmcnt(0) (own ops
//       only -> count exact; HBM latency hides under this step's compute;
//       lgkmcnt(0) closes the wave-private WAR window: next step's DMAs can't
//       land on LDS words this step's ds_reads haven't drained).
//     - NO s_barrier anywhere in the D-loop. One __syncthreads before the final
//       cross-wave reduction only.
//   Cost: H-halo staging duplication (8 staged rows per 4 output rows vs 20/16):
//   DMA x1.6, FETCH ~154->~240MB - affordable at 23% HBM. __launch_bounds__(256,4)
//   pins VGPR<=128 so 4 blocks/CU residency is guaranteed (live state ~104 regs).
// R6 (kept): aligned layout col c <-> w = wbase-2+c, 2x aligned ds_read_b128 per
//   row/array; W-edge clamp-shift fixed by in-register permute (fixl/fixr).
// R5 (kept): all lanes always issue DMA with CLAMPED global addrs; tail mask
//   (r=4: lane<32) keeps lane 0 active. H-OOB rows skipped in compute, D-OOB
//   slices skipped wave-uniformly, ring in registers.

namespace {
constexpr int Wd = 192, Hd = 192, Dd = 160;
constexpr int SH = 192;              // h stride (floats)
constexpr int SD = 192 * 192;        // d stride
constexpr long SN = (long)SD * Dd;   // n stride
constexpr int CD = 6;                // d outputs per chunk; T = CD+4 = 10
constexpr int NCHUNK = 27;           // ceil(160/6)
constexpr int TROW = 72;             // floats per row (18 16B-segs)
constexpr int ARRF = 8 * TROW;       // 576 floats: one array's 8-row block
constexpr int BUFF = 2 * ARRF;       // 1152 floats: one slice buffer (I+J)
constexpr int WREGF = 2 * BUFF;      // 2304 floats: one wave's region (2 buffers)
constexpr float INV_V = 1.0f / 125.0f;
constexpr float EPSf = 1e-5f;

__device__ __forceinline__ void wslide(const float h[8], float o[4]) {
  float s0 = h[0] + h[1] + h[2] + h[3] + h[4];
  float s1 = s0 - h[0] + h[5];
  float s2 = s1 - h[1] + h[6];
  float s3 = s2 - h[2] + h[7];
  o[0] = s0; o[1] = s1; o[2] = s2; o[3] = s3;
}

__device__ __forceinline__ void gl_lds16(const float* g, float* l) {
  __builtin_amdgcn_global_load_lds(
      (const __attribute__((address_space(1))) void*)g,
      (__attribute__((address_space(3))) void*)l, 16, 0, 0);
}
} // namespace

__global__ __launch_bounds__(256, 4) void ncc_fused(const float* __restrict__ I,
                                                    const float* __restrict__ Jv,
                                                    float* __restrict__ out) {
  __shared__ float tile[4 * WREGF];  // 4 waves x 9216 B = 36,864 B
  __shared__ float red[4];

  const int tid  = threadIdx.x;
  const int lane = tid & 63, wave = tid >> 6;
  const int tx   = lane & 15;       // w-run index (4 outputs each)
  const int tyw  = lane >> 4;       // output row within wave's 4-row strip
  const int wbase = blockIdx.x * 64;
  const int hbase = blockIdx.y * 16;
  const int n   = blockIdx.z / NCHUNK;
  const int d_lo = (blockIdx.z % NCHUNK) * CD;
  const int hw0 = hbase + 4 * wave - 2;   // region row r <-> global h = hw0 + r

  const float* Ib = I  + (long)n * SN;
  const float* Jb = Jv + (long)n * SN;
  const long  dJ  = (long)(Jb - Ib);      // per-lane array select as an offset

  // ---- wave-private staging descriptors: 288 16B-segs over 5 issues/lane ----
  // seg = r*64+lane; arr = seg>=144; rem = seg - arr*144; row = rem/18; c16 = rem%18
  // LDS float offset within buffer = seg*4 (lane-linear per issue: base + lane*16B)
  long goffL[5]; int lloc[5]; bool on[5];
  #pragma unroll
  for (int r = 0; r < 5; ++r) {
    const int seg = r * 64 + lane;
    on[r] = (r < 4) || (lane < 32);              // 288 = 4*64 + 32 (lane 0 active)
    const int arr = (seg >= 144) ? 1 : 0;
    const int rem = seg - arr * 144;
    const int row = rem / 18, c16 = rem % 18;
    const int hh = hw0 + row;
    const int hc = min(max(hh, 0), Hd - 1);      // CLAMP, never mask
    const int gw = wbase - 2 + c16 * 4;
    const int gc = min(max(gw, 0), Wd - 4);
    goffL[r] = (arr ? dJ : 0L) + (long)(hc * SH + gc);
    lloc[r]  = seg * 4;                          // float offset
  }
  float* wreg = &tile[wave * WREGF];

  // ---- prologue: stage slice d_lo-2 into buf0 (wave-private, no barrier) ----
  if (d_lo > 0) {
    const float* base = Ib + (long)(d_lo - 2) * SD;
    #pragma unroll
    for (int r = 0; r < 5; ++r) if (on[r]) gl_lds16(base + goffL[r], wreg + lloc[r]);
  }
  asm volatile("s_waitcnt vmcnt(0) lgkmcnt(0)" ::: "memory");

  // W-edge fixups (layout col c <-> w = wbase-2+c): clamp-shifted segs only touch
  // these 2 thread-columns; true values live in other slots of the same read.
  const bool fixl = (wbase == 0)   && (tx == 0);
  const bool fixr = (wbase == 128) && (tx == 15);

  float ring[5][5][4];  // [phase][channel:{I,J,II,JJ,IJ}][k]
  float acc = 0.0f;

  int bcur = 0;  // current-slice buffer (0/1)
  constexpr int T = CD + 4; // 10 steps; output d = d_lo + t - 4 for t>=4
  for (int t0 = 0; t0 < T; t0 += 5) {
    #pragma unroll
    for (int p = 0; p < 5; ++p) {             // phase = t % 5 (compile-time)
      const int t = t0 + p;
      const int s = d_lo - 2 + t;             // slice in buf[bcur]

      // ---- private prefetch: slice s+1 -> buf[bcur^1], consumed next step ----
      const bool issue = ((t + 1) < T) && ((s + 1) >= 0) && ((s + 1) < Dd);
      if (issue) {
        const float* base = Ib + (long)(s + 1) * SD;
        float* dst = wreg + (bcur ^ 1) * BUFF;
        #pragma unroll
        for (int r = 0; r < 5; ++r) if (on[r]) gl_lds16(base + goffL[r], dst + lloc[r]);
      }

      // ---- H-window accumulate from private buffer ----
      float hsI[8], hsJ[8], hsII[8], hsJJ[8], hsIJ[8];
      #pragma unroll
      for (int c = 0; c < 8; ++c) {
        hsI[c] = 0.f; hsJ[c] = 0.f; hsII[c] = 0.f; hsJJ[c] = 0.f; hsIJ[c] = 0.f;
      }
      if (s >= 0 && s < Dd) {
        const float* bufc = wreg + bcur * BUFF;
        #pragma unroll
        for (int dh = 0; dh < 5; ++dh) {
          const int rrow = tyw + dh;           // region rows tyw..tyw+4 (of 8)
          const int hh = hw0 + rrow;
          if (hh >= 0 && hh < Hd) {            // skip clamped-duplicate halo rows
            const float* pa = bufc + rrow * TROW + 4 * tx;  // cols 4tx..4tx+7, 16B-aligned
            const float* pb = pa + ARRF;       // J block
            float a[8], b[8];
            ((float4*)a)[0] = ((const float4*)pa)[0];
            ((float4*)a)[1] = ((const float4*)pa)[1];
            ((float4*)b)[0] = ((const float4*)pb)[0];
            ((float4*)b)[1] = ((const float4*)pb)[1];
            if (fixl) { a[2]=a[0]; a[3]=a[1]; a[0]=0.f; a[1]=0.f;
                        b[2]=b[0]; b[3]=b[1]; b[0]=0.f; b[1]=0.f; }
            if (fixr) { a[4]=a[6]; a[5]=a[7]; a[6]=0.f; a[7]=0.f;
                        b[4]=b[6]; b[5]=b[7]; b[6]=0.f; b[7]=0.f; }
            #pragma unroll
            for (int c = 0; c < 8; ++c) {
              const float x = a[c], y = b[c];  // cols w0-2..w0+5
              hsI[c]  += x;
              hsJ[c]  += y;
              hsII[c] = fmaf(x, x, hsII[c]);
              hsJJ[c] = fmaf(y, y, hsJJ[c]);
              hsIJ[c] = fmaf(x, y, hsIJ[c]);
            }
          }
        }
      }

      // ---- W-window sliding sums -> ring ----
      wslide(hsI,  ring[p][0]);
      wslide(hsJ,  ring[p][1]);
      wslide(hsII, ring[p][2]);
      wslide(hsJJ, ring[p][3]);
      wslide(hsIJ, ring[p][4]);

      // ---- D-window + cc ----
      const int d = d_lo + t - 4;
      if (t >= 4 && d < Dd) {
        #pragma unroll
        for (int k = 0; k < 4; ++k) {
          float SI = 0.f, SJ = 0.f, SII = 0.f, SJJ = 0.f, SIJ = 0.f;
          #pragma unroll
          for (int q = 0; q < 5; ++q) {
            SI  += ring[q][0][k];
            SJ  += ring[q][1][k];
            SII += ring[q][2][k];
            SJJ += ring[q][3][k];
            SIJ += ring[q][4][k];
          }
          const float cross = SIJ - SI * SJ * INV_V;
          const float vI    = SII - SI * SI * INV_V;
          const float vJ    = SJJ - SJ * SJ * INV_V;
          acc += cross * cross / (vI * vJ + EPSf);
        }
      }

      // ---- wave-private drain: own prefetch landed, own ds_reads retired ----
      asm volatile("s_waitcnt vmcnt(0) lgkmcnt(0)" ::: "memory");
      bcur ^= 1;
    }
  }

  // ---- block reduction -> single atomic per block (only barrier in kernel) ----
  #pragma unroll
  for (int off = 32; off > 0; off >>= 1) acc += __shfl_xor(acc, off, 64);
  if (lane == 0) red[wave] = acc;
  __syncthreads();
  if (tid == 0) {
    const float total = red[0] + red[1] + red[2] + red[3];
    atomicAdd(out, total * (-1.0f / 11796480.0f)); // -mean over 2*160*192*192
  }
}

extern "C" void kernel_launch(void* const* d_in, const int* in_sizes, int n_in,
                              void* d_out, int out_size, void* d_ws, size_t ws_size,
                              hipStream_t stream) {
  const float* I = (const float*)d_in[0];
  const float* J = (const float*)d_in[1];
  float* out = (float*)d_out;
  hipMemsetAsync(out, 0, sizeof(float), stream);
  dim3 grid(3, 12, 2 * NCHUNK); // W tiles * H tiles * (n x 27 d-chunks of 6)
  ncc_fused<<<grid, 256, 0, stream>>>(I, J, out);
}

// Round 6
// 163.024 us; speedup vs baseline: 3.3219x; 3.3219x over previous
//
#include <hip/hip_runtime.h>

// NCC loss, fused single pass. Layout [n][1][d][h][w], n=2, d=160, h=192, w=192, f32.
// R11: R10 (barrier-free wave-private structure) with the occupancy clamp REMOVED.
//   R10 was confounded: __launch_bounds__(256,4) re-triggered R3's known failure --
//   compiler clamped to 64 VGPR, spilled the 100-float ring to scratch
//   (WRITE_SIZE 60KB -> 994MB, FETCH 154->825MB, dur 461us, VALUBusy 9%). The
//   barrier-free protocol itself PASSED (absmax 0) and occupancy rose to 42% as
//   predicted; the test of the sync-skew theory was just buried under spill I/O.
//   R11 changes exactly one thing: __launch_bounds__(256) with no min-waves arg.
//   Expected envelope: ~100-112 VGPR (<=128 tier -> 4 waves/SIMD), LDS 36.9KB ->
//   4 blocks/CU. Clean A/B of: barrier-coupled 4-wave step (R9, 85us, occ 19%)
//   vs free-running waves with private distance-1 prefetch (this).
// R10 (kept): each wave fully independent. Wave w owns output rows hbase+4w..+3,
//   stages its own 8 input rows (4+4 H-halo) of BOTH arrays into a private LDS
//   region (2 buffers). Per-lane array select via global-address offset (legal:
//   only the LDS dest is lane-linear, m104/m108). Distance-1 private prefetch:
//   top of step t issues 5 DMAs for slice s+1 into buf^1; bottom of step waits
//   s_waitcnt vmcnt(0) lgkmcnt(0) (own ops only -> exact; HBM latency hides under
//   the step's compute; lgkmcnt(0) closes the wave-private WAR window). NO
//   s_barrier in the D-loop; one __syncthreads before the final reduction.
//   Cost: H-halo staging duplication -> FETCH ~1.6x (affordable at 23% HBM).
// R6 (kept): aligned layout col c <-> w = wbase-2+c, 2x aligned ds_read_b128 per
//   row/array; W-edge clamp-shift fixed by in-register permute (fixl/fixr).
// R5 (kept): all lanes always issue DMA with CLAMPED global addrs; tail mask
//   (r=4: lane<32) keeps lane 0 active. H-OOB rows skipped in compute, D-OOB
//   slices skipped wave-uniformly, ring in registers, NO occupancy clamp.

namespace {
constexpr int Wd = 192, Hd = 192, Dd = 160;
constexpr int SH = 192;              // h stride (floats)
constexpr int SD = 192 * 192;        // d stride
constexpr long SN = (long)SD * Dd;   // n stride
constexpr int CD = 6;                // d outputs per chunk; T = CD+4 = 10
constexpr int NCHUNK = 27;           // ceil(160/6)
constexpr int TROW = 72;             // floats per row (18 16B-segs)
constexpr int ARRF = 8 * TROW;       // 576 floats: one array's 8-row block
constexpr int BUFF = 2 * ARRF;       // 1152 floats: one slice buffer (I+J)
constexpr int WREGF = 2 * BUFF;      // 2304 floats: one wave's region (2 buffers)
constexpr float INV_V = 1.0f / 125.0f;
constexpr float EPSf = 1e-5f;

__device__ __forceinline__ void wslide(const float h[8], float o[4]) {
  float s0 = h[0] + h[1] + h[2] + h[3] + h[4];
  float s1 = s0 - h[0] + h[5];
  float s2 = s1 - h[1] + h[6];
  float s3 = s2 - h[2] + h[7];
  o[0] = s0; o[1] = s1; o[2] = s2; o[3] = s3;
}

__device__ __forceinline__ void gl_lds16(const float* g, float* l) {
  __builtin_amdgcn_global_load_lds(
      (const __attribute__((address_space(1))) void*)g,
      (__attribute__((address_space(3))) void*)l, 16, 0, 0);
}
} // namespace

__global__ __launch_bounds__(256) void ncc_fused(const float* __restrict__ I,
                                                 const float* __restrict__ Jv,
                                                 float* __restrict__ out) {
  __shared__ float tile[4 * WREGF];  // 4 waves x 9216 B = 36,864 B
  __shared__ float red[4];

  const int tid  = threadIdx.x;
  const int lane = tid & 63, wave = tid >> 6;
  const int tx   = lane & 15;       // w-run index (4 outputs each)
  const int tyw  = lane >> 4;       // output row within wave's 4-row strip
  const int wbase = blockIdx.x * 64;
  const int hbase = blockIdx.y * 16;
  const int n   = blockIdx.z / NCHUNK;
  const int d_lo = (blockIdx.z % NCHUNK) * CD;
  const int hw0 = hbase + 4 * wave - 2;   // region row r <-> global h = hw0 + r

  const float* Ib = I  + (long)n * SN;
  const float* Jb = Jv + (long)n * SN;
  const long  dJ  = (long)(Jb - Ib);      // per-lane array select as an offset

  // ---- wave-private staging descriptors: 288 16B-segs over 5 issues/lane ----
  // seg = r*64+lane; arr = seg>=144; rem = seg - arr*144; row = rem/18; c16 = rem%18
  // LDS float offset within buffer = seg*4 (lane-linear per issue: base + lane*16B)
  long goffL[5]; int lloc[5]; bool on[5];
  #pragma unroll
  for (int r = 0; r < 5; ++r) {
    const int seg = r * 64 + lane;
    on[r] = (r < 4) || (lane < 32);              // 288 = 4*64 + 32 (lane 0 active)
    const int arr = (seg >= 144) ? 1 : 0;
    const int rem = seg - arr * 144;
    const int row = rem / 18, c16 = rem % 18;
    const int hh = hw0 + row;
    const int hc = min(max(hh, 0), Hd - 1);      // CLAMP, never mask
    const int gw = wbase - 2 + c16 * 4;
    const int gc = min(max(gw, 0), Wd - 4);
    goffL[r] = (arr ? dJ : 0L) + (long)(hc * SH + gc);
    lloc[r]  = seg * 4;                          // float offset
  }
  float* wreg = &tile[wave * WREGF];

  // ---- prologue: stage slice d_lo-2 into buf0 (wave-private, no barrier) ----
  if (d_lo > 0) {
    const float* base = Ib + (long)(d_lo - 2) * SD;
    #pragma unroll
    for (int r = 0; r < 5; ++r) if (on[r]) gl_lds16(base + goffL[r], wreg + lloc[r]);
  }
  asm volatile("s_waitcnt vmcnt(0) lgkmcnt(0)" ::: "memory");

  // W-edge fixups (layout col c <-> w = wbase-2+c): clamp-shifted segs only touch
  // these 2 thread-columns; true values live in other slots of the same read.
  const bool fixl = (wbase == 0)   && (tx == 0);
  const bool fixr = (wbase == 128) && (tx == 15);

  float ring[5][5][4];  // [phase][channel:{I,J,II,JJ,IJ}][k]
  float acc = 0.0f;

  int bcur = 0;  // current-slice buffer (0/1)
  constexpr int T = CD + 4; // 10 steps; output d = d_lo + t - 4 for t>=4
  for (int t0 = 0; t0 < T; t0 += 5) {
    #pragma unroll
    for (int p = 0; p < 5; ++p) {             // phase = t % 5 (compile-time)
      const int t = t0 + p;
      const int s = d_lo - 2 + t;             // slice in buf[bcur]

      // ---- private prefetch: slice s+1 -> buf[bcur^1], consumed next step ----
      const bool issue = ((t + 1) < T) && ((s + 1) >= 0) && ((s + 1) < Dd);
      if (issue) {
        const float* base = Ib + (long)(s + 1) * SD;
        float* dst = wreg + (bcur ^ 1) * BUFF;
        #pragma unroll
        for (int r = 0; r < 5; ++r) if (on[r]) gl_lds16(base + goffL[r], dst + lloc[r]);
      }

      // ---- H-window accumulate from private buffer ----
      float hsI[8], hsJ[8], hsII[8], hsJJ[8], hsIJ[8];
      #pragma unroll
      for (int c = 0; c < 8; ++c) {
        hsI[c] = 0.f; hsJ[c] = 0.f; hsII[c] = 0.f; hsJJ[c] = 0.f; hsIJ[c] = 0.f;
      }
      if (s >= 0 && s < Dd) {
        const float* bufc = wreg + bcur * BUFF;
        #pragma unroll
        for (int dh = 0; dh < 5; ++dh) {
          const int rrow = tyw + dh;           // region rows tyw..tyw+4 (of 8)
          const int hh = hw0 + rrow;
          if (hh >= 0 && hh < Hd) {            // skip clamped-duplicate halo rows
            const float* pa = bufc + rrow * TROW + 4 * tx;  // cols 4tx..4tx+7, 16B-aligned
            const float* pb = pa + ARRF;       // J block
            float a[8], b[8];
            ((float4*)a)[0] = ((const float4*)pa)[0];
            ((float4*)a)[1] = ((const float4*)pa)[1];
            ((float4*)b)[0] = ((const float4*)pb)[0];
            ((float4*)b)[1] = ((const float4*)pb)[1];
            if (fixl) { a[2]=a[0]; a[3]=a[1]; a[0]=0.f; a[1]=0.f;
                        b[2]=b[0]; b[3]=b[1]; b[0]=0.f; b[1]=0.f; }
            if (fixr) { a[4]=a[6]; a[5]=a[7]; a[6]=0.f; a[7]=0.f;
                        b[4]=b[6]; b[5]=b[7]; b[6]=0.f; b[7]=0.f; }
            #pragma unroll
            for (int c = 0; c < 8; ++c) {
              const float x = a[c], y = b[c];  // cols w0-2..w0+5
              hsI[c]  += x;
              hsJ[c]  += y;
              hsII[c] = fmaf(x, x, hsII[c]);
              hsJJ[c] = fmaf(y, y, hsJJ[c]);
              hsIJ[c] = fmaf(x, y, hsIJ[c]);
            }
          }
        }
      }

      // ---- W-window sliding sums -> ring ----
      wslide(hsI,  ring[p][0]);
      wslide(hsJ,  ring[p][1]);
      wslide(hsII, ring[p][2]);
      wslide(hsJJ, ring[p][3]);
      wslide(hsIJ, ring[p][4]);

      // ---- D-window + cc ----
      const int d = d_lo + t - 4;
      if (t >= 4 && d < Dd) {
        #pragma unroll
        for (int k = 0; k < 4; ++k) {
          float SI = 0.f, SJ = 0.f, SII = 0.f, SJJ = 0.f, SIJ = 0.f;
          #pragma unroll
          for (int q = 0; q < 5; ++q) {
            SI  += ring[q][0][k];
            SJ  += ring[q][1][k];
            SII += ring[q][2][k];
            SJJ += ring[q][3][k];
            SIJ += ring[q][4][k];
          }
          const float cross = SIJ - SI * SJ * INV_V;
          const float vI    = SII - SI * SI * INV_V;
          const float vJ    = SJJ - SJ * SJ * INV_V;
          acc += cross * cross / (vI * vJ + EPSf);
        }
      }

      // ---- wave-private drain: own prefetch landed, own ds_reads retired ----
      asm volatile("s_waitcnt vmcnt(0) lgkmcnt(0)" ::: "memory");
      bcur ^= 1;
    }
  }

  // ---- block reduction -> single atomic per block (only barrier in kernel) ----
  #pragma unroll
  for (int off = 32; off > 0; off >>= 1) acc += __shfl_xor(acc, off, 64);
  if (lane == 0) red[wave] = acc;
  __syncthreads();
  if (tid == 0) {
    const float total = red[0] + red[1] + red[2] + red[3];
    atomicAdd(out, total * (-1.0f / 11796480.0f)); // -mean over 2*160*192*192
  }
}

extern "C" void kernel_launch(void* const* d_in, const int* in_sizes, int n_in,
                              void* d_out, int out_size, void* d_ws, size_t ws_size,
                              hipStream_t stream) {
  const float* I = (const float*)d_in[0];
  const float* J = (const float*)d_in[1];
  float* out = (float*)d_out;
  hipMemsetAsync(out, 0, sizeof(float), stream);
  dim3 grid(3, 12, 2 * NCHUNK); // W tiles * H tiles * (n x 27 d-chunks of 6)
  ncc_fused<<<grid, 256, 0, stream>>>(I, J, out);
}

// Round 7
// 161.832 us; speedup vs baseline: 3.3464x; 1.0074x over previous
//
#include <hip/hip_runtime.h>

// NCC loss, fused single pass. Layout [n][1][d][h][w], n=2, d=160, h=192, w=192, f32.
// R12: break the per-row load->use serialization. Evidence trail: dur is pinned at
//   81-85us across R6 (-33% LDS reads), R9 (counted-vmcnt DMA pipeline), R11 (zero
//   barriers, wave-private prefetch); VALUBusy stuck 48-55%; SQ_LDS_BANK_CONFLICT
//   bit-identical 6,031,872 across all. The one structure every version kept: the
//   inner 5-row loop guards each row with `if (hh>=0 && hh<Hd)` where hh is
//   PER-LANE (tyw) -> divergent-capable branch -> compiler cannot hoist row r+1's
//   ds_read_b128 above row r's exec-guarded region -> 5 serialized
//   {4x ds_read -> 40 dependent VALU} chains per step -> ~50% per-wave duty cycle.
//   Fix: `interior = (hw0>=0 && hw0+7<Hd)` is WAVE-UNIFORM and true for 46/48
//   waves. Fast path: straight-line fully-unrolled 5-row body, row r+1's 4 float4
//   loads issued BEFORE row r's accumulation (one-row software pipeline, ~80 VALU
//   cycles of load->use cover). Slow path (2 H-edge waves): R11's guarded loop.
// R11 (kept): barrier-free wave-private structure. Wave w owns output rows
//   hbase+4w..+3, stages its own 8 input rows (4+4 halo) of BOTH arrays into a
//   private 2-buffer LDS region; per-lane array select via global-address offset
//   (legal: only the LDS dest is lane-linear, m104/m108). Distance-1 private
//   prefetch: top of step issues 5 DMAs for slice s+1; bottom waits
//   s_waitcnt vmcnt(0) lgkmcnt(0) (own ops only; lgkmcnt closes the WAR window).
//   NO s_barrier in the D-loop.
// R6 (kept): aligned layout col c <-> w = wbase-2+c, 2x aligned ds_read_b128 per
//   row/array; W-edge clamp-shift fixed by in-register permute (fixl/fixr).
// R5 (kept): all lanes always issue DMA with CLAMPED global addrs; tail mask
//   (r=4: lane<32) keeps lane 0 active. D-OOB slices skipped uniformly, ring in
//   registers, NO occupancy clamp (R3/R10: (256,4) spills the ring -> 1GB scratch).

namespace {
constexpr int Wd = 192, Hd = 192, Dd = 160;
constexpr int SH = 192;              // h stride (floats)
constexpr int SD = 192 * 192;        // d stride
constexpr long SN = (long)SD * Dd;   // n stride
constexpr int CD = 6;                // d outputs per chunk; T = CD+4 = 10
constexpr int NCHUNK = 27;           // ceil(160/6)
constexpr int TROW = 72;             // floats per row (18 16B-segs)
constexpr int ARRF = 8 * TROW;       // 576 floats: one array's 8-row block
constexpr int BUFF = 2 * ARRF;       // 1152 floats: one slice buffer (I+J)
constexpr int WREGF = 2 * BUFF;      // 2304 floats: one wave's region (2 buffers)
constexpr float INV_V = 1.0f / 125.0f;
constexpr float EPSf = 1e-5f;

__device__ __forceinline__ void wslide(const float h[8], float o[4]) {
  float s0 = h[0] + h[1] + h[2] + h[3] + h[4];
  float s1 = s0 - h[0] + h[5];
  float s2 = s1 - h[1] + h[6];
  float s3 = s2 - h[2] + h[7];
  o[0] = s0; o[1] = s1; o[2] = s2; o[3] = s3;
}

__device__ __forceinline__ void gl_lds16(const float* g, float* l) {
  __builtin_amdgcn_global_load_lds(
      (const __attribute__((address_space(1))) void*)g,
      (__attribute__((address_space(3))) void*)l, 16, 0, 0);
}
} // namespace

__global__ __launch_bounds__(256) void ncc_fused(const float* __restrict__ I,
                                                 const float* __restrict__ Jv,
                                                 float* __restrict__ out) {
  __shared__ float tile[4 * WREGF];  // 4 waves x 9216 B = 36,864 B
  __shared__ float red[4];

  const int tid  = threadIdx.x;
  const int lane = tid & 63, wave = tid >> 6;
  const int tx   = lane & 15;       // w-run index (4 outputs each)
  const int tyw  = lane >> 4;       // output row within wave's 4-row strip
  const int wbase = blockIdx.x * 64;
  const int hbase = blockIdx.y * 16;
  const int n   = blockIdx.z / NCHUNK;
  const int d_lo = (blockIdx.z % NCHUNK) * CD;
  const int hw0 = hbase + 4 * wave - 2;   // region row r <-> global h = hw0 + r
  const bool interior = (hw0 >= 0) && (hw0 + 7 < Hd);  // wave-uniform: 46/48 waves

  const float* Ib = I  + (long)n * SN;
  const float* Jb = Jv + (long)n * SN;
  const long  dJ  = (long)(Jb - Ib);      // per-lane array select as an offset

  // ---- wave-private staging descriptors: 288 16B-segs over 5 issues/lane ----
  // seg = r*64+lane; arr = seg>=144; rem = seg - arr*144; row = rem/18; c16 = rem%18
  // LDS float offset within buffer = seg*4 (lane-linear per issue: base + lane*16B)
  long goffL[5]; int lloc[5]; bool on[5];
  #pragma unroll
  for (int r = 0; r < 5; ++r) {
    const int seg = r * 64 + lane;
    on[r] = (r < 4) || (lane < 32);              // 288 = 4*64 + 32 (lane 0 active)
    const int arr = (seg >= 144) ? 1 : 0;
    const int rem = seg - arr * 144;
    const int row = rem / 18, c16 = rem % 18;
    const int hh = hw0 + row;
    const int hc = min(max(hh, 0), Hd - 1);      // CLAMP, never mask
    const int gw = wbase - 2 + c16 * 4;
    const int gc = min(max(gw, 0), Wd - 4);
    goffL[r] = (arr ? dJ : 0L) + (long)(hc * SH + gc);
    lloc[r]  = seg * 4;                          // float offset
  }
  float* wreg = &tile[wave * WREGF];

  // ---- prologue: stage slice d_lo-2 into buf0 (wave-private, no barrier) ----
  if (d_lo > 0) {
    const float* base = Ib + (long)(d_lo - 2) * SD;
    #pragma unroll
    for (int r = 0; r < 5; ++r) if (on[r]) gl_lds16(base + goffL[r], wreg + lloc[r]);
  }
  asm volatile("s_waitcnt vmcnt(0) lgkmcnt(0)" ::: "memory");

  // W-edge fixups (layout col c <-> w = wbase-2+c): clamp-shifted segs only touch
  // these 2 thread-columns; true values live in other slots of the same read.
  const bool fixl = (wbase == 0)   && (tx == 0);
  const bool fixr = (wbase == 128) && (tx == 15);

  float ring[5][5][4];  // [phase][channel:{I,J,II,JJ,IJ}][k]
  float acc = 0.0f;

  int bcur = 0;  // current-slice buffer (0/1)
  constexpr int T = CD + 4; // 10 steps; output d = d_lo + t - 4 for t>=4
  for (int t0 = 0; t0 < T; t0 += 5) {
    #pragma unroll
    for (int p = 0; p < 5; ++p) {             // phase = t % 5 (compile-time)
      const int t = t0 + p;
      const int s = d_lo - 2 + t;             // slice in buf[bcur]

      // ---- private prefetch: slice s+1 -> buf[bcur^1], consumed next step ----
      const bool issue = ((t + 1) < T) && ((s + 1) >= 0) && ((s + 1) < Dd);
      if (issue) {
        const float* base = Ib + (long)(s + 1) * SD;
        float* dst = wreg + (bcur ^ 1) * BUFF;
        #pragma unroll
        for (int r = 0; r < 5; ++r) if (on[r]) gl_lds16(base + goffL[r], dst + lloc[r]);
      }

      // ---- H-window accumulate from private buffer ----
      float hsI[8], hsJ[8], hsII[8], hsJJ[8], hsIJ[8];
      #pragma unroll
      for (int c = 0; c < 8; ++c) {
        hsI[c] = 0.f; hsJ[c] = 0.f; hsII[c] = 0.f; hsJJ[c] = 0.f; hsIJ[c] = 0.f;
      }
      if (s >= 0 && s < Dd) {
        const float* bufr = wreg + bcur * BUFF + 4 * tx;  // + rrow*TROW per row
        if (interior) {
          // ---- FAST PATH: straight-line, one-row-ahead software pipeline ----
          const float* p0 = bufr + tyw * TROW;
          float4 A0 = ((const float4*)p0)[0];
          float4 A1 = ((const float4*)p0)[1];
          float4 B0 = ((const float4*)(p0 + ARRF))[0];
          float4 B1 = ((const float4*)(p0 + ARRF))[1];
          #pragma unroll
          for (int dh = 0; dh < 5; ++dh) {
            float4 nA0, nA1, nB0, nB1;
            if (dh < 4) {                       // issue next row's loads FIRST
              const float* pn = bufr + (tyw + dh + 1) * TROW;
              nA0 = ((const float4*)pn)[0];
              nA1 = ((const float4*)pn)[1];
              nB0 = ((const float4*)(pn + ARRF))[0];
              nB1 = ((const float4*)(pn + ARRF))[1];
            }
            float a[8], b[8];
            ((float4*)a)[0] = A0; ((float4*)a)[1] = A1;
            ((float4*)b)[0] = B0; ((float4*)b)[1] = B1;
            if (fixl) { a[2]=a[0]; a[3]=a[1]; a[0]=0.f; a[1]=0.f;
                        b[2]=b[0]; b[3]=b[1]; b[0]=0.f; b[1]=0.f; }
            if (fixr) { a[4]=a[6]; a[5]=a[7]; a[6]=0.f; a[7]=0.f;
                        b[4]=b[6]; b[5]=b[7]; b[6]=0.f; b[7]=0.f; }
            #pragma unroll
            for (int c = 0; c < 8; ++c) {
              const float x = a[c], y = b[c];
              hsI[c]  += x;
              hsJ[c]  += y;
              hsII[c] = fmaf(x, x, hsII[c]);
              hsJJ[c] = fmaf(y, y, hsJJ[c]);
              hsIJ[c] = fmaf(x, y, hsIJ[c]);
            }
            A0 = nA0; A1 = nA1; B0 = nB0; B1 = nB1;
          }
        } else {
          // ---- SLOW PATH (2 H-edge waves): R11's guarded loop ----
          #pragma unroll
          for (int dh = 0; dh < 5; ++dh) {
            const int rrow = tyw + dh;
            const int hh = hw0 + rrow;
            if (hh >= 0 && hh < Hd) {          // skip clamped-duplicate halo rows
              const float* pa = bufr + rrow * TROW;
              const float* pb = pa + ARRF;
              float a[8], b[8];
              ((float4*)a)[0] = ((const float4*)pa)[0];
              ((float4*)a)[1] = ((const float4*)pa)[1];
              ((float4*)b)[0] = ((const float4*)pb)[0];
              ((float4*)b)[1] = ((const float4*)pb)[1];
              if (fixl) { a[2]=a[0]; a[3]=a[1]; a[0]=0.f; a[1]=0.f;
                          b[2]=b[0]; b[3]=b[1]; b[0]=0.f; b[1]=0.f; }
              if (fixr) { a[4]=a[6]; a[5]=a[7]; a[6]=0.f; a[7]=0.f;
                          b[4]=b[6]; b[5]=b[7]; b[6]=0.f; b[7]=0.f; }
              #pragma unroll
              for (int c = 0; c < 8; ++c) {
                const float x = a[c], y = b[c];
                hsI[c]  += x;
                hsJ[c]  += y;
                hsII[c] = fmaf(x, x, hsII[c]);
                hsJJ[c] = fmaf(y, y, hsJJ[c]);
                hsIJ[c] = fmaf(x, y, hsIJ[c]);
              }
            }
          }
        }
      }

      // ---- W-window sliding sums -> ring ----
      wslide(hsI,  ring[p][0]);
      wslide(hsJ,  ring[p][1]);
      wslide(hsII, ring[p][2]);
      wslide(hsJJ, ring[p][3]);
      wslide(hsIJ, ring[p][4]);

      // ---- D-window + cc ----
      const int d = d_lo + t - 4;
      if (t >= 4 && d < Dd) {
        #pragma unroll
        for (int k = 0; k < 4; ++k) {
          float SI = 0.f, SJ = 0.f, SII = 0.f, SJJ = 0.f, SIJ = 0.f;
          #pragma unroll
          for (int q = 0; q < 5; ++q) {
            SI  += ring[q][0][k];
            SJ  += ring[q][1][k];
            SII += ring[q][2][k];
            SJJ += ring[q][3][k];
            SIJ += ring[q][4][k];
          }
          const float cross = SIJ - SI * SJ * INV_V;
          const float vI    = SII - SI * SI * INV_V;
          const float vJ    = SJJ - SJ * SJ * INV_V;
          acc += cross * cross / (vI * vJ + EPSf);
        }
      }

      // ---- wave-private drain: own prefetch landed, own ds_reads retired ----
      asm volatile("s_waitcnt vmcnt(0) lgkmcnt(0)" ::: "memory");
      bcur ^= 1;
    }
  }

  // ---- block reduction -> single atomic per block (only barrier in kernel) ----
  #pragma unroll
  for (int off = 32; off > 0; off >>= 1) acc += __shfl_xor(acc, off, 64);
  if (lane == 0) red[wave] = acc;
  __syncthreads();
  if (tid == 0) {
    const float total = red[0] + red[1] + red[2] + red[3];
    atomicAdd(out, total * (-1.0f / 11796480.0f)); // -mean over 2*160*192*192
  }
}

extern "C" void kernel_launch(void* const* d_in, const int* in_sizes, int n_in,
                              void* d_out, int out_size, void* d_ws, size_t ws_size,
                              hipStream_t stream) {
  const float* I = (const float*)d_in[0];
  const float* J = (const float*)d_in[1];
  float* out = (float*)d_out;
  hipMemsetAsync(out, 0, sizeof(float), stream);
  dim3 grid(3, 12, 2 * NCHUNK); // W tiles * H tiles * (n x 27 d-chunks of 6)
  ncc_fused<<<grid, 256, 0, stream>>>(I, J, out);
}